// Round 11
// baseline (356.141 us; speedup 1.0000x reference)
//
#include <hip/hip_runtime.h>
#include <hip/hip_bf16.h>

#define B_ 2048
#define LC_ 20
#define LX_ 20
#define LH_ 200
#define D_ 128
#define H_ 512
#define DENSE_ 256

typedef __attribute__((ext_vector_type(8))) short short8v;
typedef __attribute__((ext_vector_type(4))) short short4v;
typedef __attribute__((ext_vector_type(4))) float floatx4;

__device__ __forceinline__ float siluf(float x) { return x / (1.f + __expf(-x)); }

__device__ __forceinline__ unsigned short f2bf(float f) {
  return __builtin_bit_cast(unsigned short, __float2bfloat16(f));
}
__device__ __forceinline__ float bf2f(unsigned short u) {
  return __bfloat162float(__builtin_bit_cast(__hip_bfloat16, u));
}

__device__ __forceinline__ float wredsum(float v) {
#pragma unroll
  for (int off = 32; off > 0; off >>= 1) v += __shfl_xor(v, off, 64);
  return v;
}

// pair index into the 15-entry upper-triangular (p<=q, 5x5) list
__device__ __forceinline__ int cidx(int a, int b) {
  if (a > b) { int t = a; a = b; b = t; }
  const int base[5] = {0, 5, 9, 12, 14};
  return base[a] + (b - a);
}

// ---------------------------------------------------------------------------
// k0ab: fused k0a+k0b. DIAGNOSTIC rep loop (idempotent).
__global__ __launch_bounds__(256) void k0ab(
    const float* __restrict__ w1, const float* __restrict__ b1,
    const float* __restrict__ W2, const float* __restrict__ b2,
    const float* __restrict__ grp_emb, const float* __restrict__ comp_w,
    const float* __restrict__ comp_b,
    float* __restrict__ E, float* __restrict__ F, float* __restrict__ gvec,
    int rep) {
  __shared__ float sc[128];
  __shared__ float spart[2][128];
  __shared__ float sE[128];
  int tid = threadIdx.x;
  int j = tid & 127, kh = tid >> 7;  // kh in {0,1}
  int blk = blockIdx.x;
  for (int r0 = 0; r0 < rep; ++r0) {
    if (blk < 5) {
      if (tid < 128) {
        float w = w1[j], bb = b1[j];
        float y0 = siluf(bb);
        float y1 = siluf(0.25f * w + bb);
        float y2 = siluf(0.50f * w + bb);
        float y3 = siluf(0.75f * w + bb);
        float y4 = siluf(w + bb);
        float d1 = y1 - y0;
        float d2 = y2 - 2.f * y1 + y0;
        float d3 = y3 - 3.f * y2 + 3.f * y1 - y0;
        float d4 = y4 - 4.f * y3 + 6.f * y2 - 4.f * y1 + y0;
        float c0 = y0;
        float c1 = d1 - 0.5f * d2 + d3 * (1.f / 3.f) - 0.25f * d4;
        float c2 = 0.5f * d2 - 0.5f * d3 + (11.f / 24.f) * d4;
        float c3 = d3 * (1.f / 6.f) - 0.25f * d4;
        float c4 = d4 * (1.f / 24.f);
        float cp;
        int p = blk;
        if (p == 0) cp = c0;
        else if (p == 1) cp = c1 * 4.f;
        else if (p == 2) cp = c2 * 16.f;
        else if (p == 3) cp = c3 * 64.f;
        else cp = c4 * 256.f;
        sc[j] = cp;
      }
      __syncthreads();
      float acc = 0.f;
#pragma unroll 8
      for (int kk = kh * 64; kk < kh * 64 + 64; ++kk) acc += sc[kk] * W2[kk * 128 + j];
      spart[kh][j] = acc;
      __syncthreads();
      if (tid < 128) {
        float e = spart[0][j] + spart[1][j];
        if (blk == 0) e += b2[j];
        E[blk * 128 + j] = e;
        sE[j] = e;
      }
      __syncthreads();
      acc = 0.f;
#pragma unroll 8
      for (int kk = kh * 64; kk < kh * 64 + 64; ++kk)
        acc += sE[kk] * comp_w[(128 + kk) * 128 + j];
      spart[kh][j] = acc;
      __syncthreads();
      if (tid < 128) {
        float f = spart[0][j] + spart[1][j];
        if (blk == 0) f += comp_b[j];
        F[blk * 128 + j] = f;
      }
    } else {
      int g = blk - 5;
      if (tid < 128) sc[j] = grp_emb[g * 128 + j];
      __syncthreads();
      float acc = 0.f;
#pragma unroll 8
      for (int kk = kh * 64; kk < kh * 64 + 64; ++kk)
        acc += sc[kk] * comp_w[kk * 128 + j];
      spart[kh][j] = acc;
      __syncthreads();
      if (tid < 128) gvec[g * 128 + j] = spart[0][j] + spart[1][j];
    }
    __syncthreads();
  }
}

// ---------------------------------------------------------------------------
// k0c: 48 channel-moments + LN moment polys + Chebyshev fits -> CC.
// DIAGNOSTIC rep loop. 1 block, 512 threads.
__global__ __launch_bounds__(512) void k0c_fit(
    const float* __restrict__ F, const float* __restrict__ gvec,
    const float* __restrict__ cg_, const float* __restrict__ cbt_,
    float* __restrict__ CC, int rep) {
  __shared__ float sF2[640];
  __shared__ float sGv[512];
  __shared__ float s48[48];
  __shared__ float sMC[20], sVC[36];
  int tid = threadIdx.x;
  for (int r0 = 0; r0 < rep; ++r0) {
    for (int idx = tid; idx < 640; idx += 512) sF2[idx] = F[idx];
    if (tid < 512) sGv[tid] = gvec[tid];
    __syncthreads();
    int wv = tid >> 6, lane = tid & 63;
#pragma unroll
    for (int i = 0; i < 6; ++i) {
      int m = wv * 6 + i;
      if (m < 48) {
        const float* va;
        const float* vb = nullptr;
        int t = m;
        if (t < 5) va = &sF2[t * 128];
        else if (t < 9) va = &sGv[(t - 5) * 128];
        else if (t < 13) { va = &sGv[(t - 9) * 128]; vb = va; }
        else if (t < 33) {
          int g = (t - 13) / 5, p = (t - 13) % 5;
          va = &sGv[g * 128]; vb = &sF2[p * 128];
        } else {
          int idx = t - 33;
          int a = 0;
          if (idx >= 14) a = 4;
          else if (idx >= 12) a = 3;
          else if (idx >= 9) a = 2;
          else if (idx >= 5) a = 1;
          const int base[5] = {0, 5, 9, 12, 14};
          int bcol = a + (idx - base[a]);
          va = &sF2[a * 128]; vb = &sF2[bcol * 128];
        }
        float s;
        if (vb) s = va[lane] * vb[lane] + va[lane + 64] * vb[lane + 64];
        else    s = va[lane] + va[lane + 64];
        s = wredsum(s);
        if (lane == 0) s48[m] = s * (1.f / 128.f);
      }
    }
    __syncthreads();
    if (tid < 20) {
      int g = tid / 5, p = tid % 5;
      sMC[g * 5 + p] = s48[p] + (p == 0 ? s48[5 + g] : 0.f);
    }
    if (tid < 36) {
      int g = tid / 9, kk = tid % 9;
      float v = (kk == 0 ? s48[9 + g] : 0.f);
      if (kk < 5) v += 2.f * s48[13 + g * 5 + kk];
#pragma unroll
      for (int p = 0; p < 5; ++p) {
        int q = kk - p;
        if (q >= 0 && q <= 4) v += s48[33 + cidx(p, q)];
      }
      sVC[g * 9 + kk] = v;
    }
    __syncthreads();
    const float nodes[11] = {0.f, 0.02447174185f, 0.09549150281f, 0.2061073739f,
                             0.3454915028f, 0.5f, 0.6545084972f, 0.7938926261f,
                             0.9045084972f, 0.9755282581f, 1.f};
    int g = tid >> 7, j = tid & 127;
    float cgj = cg_[j], btj = cbt_[j];
    float F0 = sF2[j], F1 = sF2[128 + j], F2v = sF2[256 + j], F3 = sF2[384 + j], F4 = sF2[512 + j];
    const float* mc = &sMC[g * 5];
    const float* vc = &sVC[g * 9];
    float gv = sGv[g * 128 + j];
    float fv[11];
#pragma unroll
    for (int n = 0; n < 11; ++n) {
      float t = nodes[n];
      float mean = (((mc[4] * t + mc[3]) * t + mc[2]) * t + mc[1]) * t + mc[0];
      float e2 = vc[8];
#pragma unroll
      for (int p = 7; p >= 0; --p) e2 = e2 * t + vc[p];
      float rstd = rsqrtf(e2 - mean * mean + 1e-5f);
      float pre = gv + ((((F4 * t + F3) * t + F2v) * t + F1) * t + F0);
      fv[n] = siluf((pre - mean) * rstd * cgj + btj);
    }
#pragma unroll
    for (int ord = 1; ord <= 10; ++ord) {
#pragma unroll
      for (int n = 10; n >= 1; --n) {
        if (n >= ord) fv[n] = (fv[n] - fv[n - 1]) / (nodes[n] - nodes[n - ord]);
      }
    }
    float c[11];
#pragma unroll
    for (int i = 0; i < 11; ++i) c[i] = 0.f;
    c[0] = fv[10];
#pragma unroll
    for (int n = 9; n >= 0; --n) {
      int deg = 9 - n;
      float x = nodes[n];
      c[deg + 1] = c[deg];
#pragma unroll
      for (int i = 10; i >= 1; --i) {
        if (i <= deg) c[i] = c[i - 1] - x * c[i];
      }
      c[0] = fv[n] - x * c[0];
    }
#pragma unroll
    for (int p = 0; p < 11; ++p) CC[(g * 11 + p) * 128 + j] = c[p];
    __syncthreads();
  }
}

// ---------------------------------------------------------------------------
// k_conv: blocks 0..175 -> out_w1 transpose; blocks 176..3695 -> misc convs.
// DIAGNOSTIC rep loop.
__global__ __launch_bounds__(256) void k_conv(
    const float* __restrict__ ow1, const float* __restrict__ ow2,
    const float* __restrict__ qw, const float* __restrict__ dw,
    const float* __restrict__ df,
    unsigned short* __restrict__ OW1BT, unsigned short* __restrict__ OW2BT,
    unsigned short* __restrict__ QWBT, unsigned short* __restrict__ DWBT,
    unsigned short* __restrict__ DB, int rep) {
  __shared__ float tile[64][65];
  int tid = threadIdx.x;
  for (int r0 = 0; r0 < rep; ++r0) {
    if (blockIdx.x < 176) {
      int bk = blockIdx.x % 22;
      int bn = blockIdx.x / 22;
      int tx = tid & 63, ty = tid >> 6;
#pragma unroll
      for (int r = 0; r < 16; ++r) {
        int kl = ty * 16 + r;
        tile[kl][tx] = ow1[(size_t)(bk * 64 + kl) * 512 + bn * 64 + tx];
      }
      __syncthreads();
#pragma unroll
      for (int r = 0; r < 16; ++r) {
        int nl = ty * 16 + r;
        OW1BT[(size_t)(bn * 64 + nl) * 1408 + bk * 64 + tx] = f2bf(tile[tx][nl]);
      }
    } else {
      int idx = (blockIdx.x - 176) * 256 + tid;
      if (idx < 131072) {
        int n = idx >> 9, k = idx & 511;
        OW2BT[(size_t)n * 512 + k] = f2bf(ow2[(size_t)k * 256 + n]);
      } else if (idx < 245760) {
        int i = idx - 131072;
        int n = i / 896, k = i - n * 896;
        QWBT[(size_t)n * 896 + k] = f2bf(qw[(size_t)k * 128 + n]);
      } else if (idx < 376832) {
        int i = idx - 245760;
        int n = i >> 8, k = i & 255;
        DWBT[(size_t)n * 256 + k] = f2bf(dw[(size_t)k * 512 + n]);
      } else {
        int i = idx - 376832;
        DB[i] = f2bf(df[i]);
      }
    }
    __syncthreads();
  }
}

// ---------------------------------------------------------------------------
// cand_s / ctx_s masked means -> FB[0:256) bf16, ballot-compacted.
// grid B_, block 256. (NOT amplified this round.)
__global__ __launch_bounds__(256) void k_candctx(
    const int* __restrict__ ctok, const int* __restrict__ xtok,
    const int* __restrict__ cmask, const int* __restrict__ xmask,
    const float* __restrict__ tok_emb, unsigned short* __restrict__ FB) {
  __shared__ int sLc[LC_], sLx[LX_];
  __shared__ int scnt[2];
  int b = blockIdx.x, tid = threadIdx.x;
  int w = tid >> 6, lane = tid & 63;
  if (w == 0) {
    int valid = 0, tok = 0;
    if (lane < LC_) {
      valid = cmask[b * LC_ + lane];
      tok = ctok[b * LC_ + lane];
    }
    unsigned long long mb = __ballot(valid != 0);
    int prefix = __popcll(mb & ((1ull << lane) - 1ull));
    if (valid) sLc[prefix] = tok;
    if (lane == 0) scnt[0] = __popcll(mb);
  } else if (w == 1) {
    int valid = 0, tok = 0;
    if (lane < LX_) {
      valid = xmask[b * LX_ + lane];
      tok = xtok[b * LX_ + lane];
    }
    unsigned long long mb = __ballot(valid != 0);
    int prefix = __popcll(mb & ((1ull << lane) - 1ull));
    if (valid) sLx[prefix] = tok;
    if (lane == 0) scnt[1] = __popcll(mb);
  }
  __syncthreads();
  int j = tid & 127, half = tid >> 7;
  float acc = 0.f;
  if (half == 0) {
    int n = scnt[0];
    for (int i = 0; i < n; ++i) acc += tok_emb[(size_t)sLc[i] * 128 + j];
    FB[(size_t)b * 1408 + j] = f2bf(acc / fmaxf((float)n, 1.f));
  } else {
    int n = scnt[1];
    for (int i = 0; i < n; ++i) acc += tok_emb[(size_t)sLx[i] * 128 + j];
    FB[(size_t)b * 1408 + 128 + j] = f2bf(acc / fmaxf((float)n, 1.f));
  }
}

// ---------------------------------------------------------------------------
// comp summary via per-(g,p) power sums + precomputed poly CC. grid B_, 256
__global__ __launch_bounds__(256) void k_comp_pow(
    const float* __restrict__ times, const int* __restrict__ groups,
    const int* __restrict__ hmask, const float* __restrict__ CC,
    unsigned short* __restrict__ FB) {
  __shared__ float sPow[LH_ * 11];
  __shared__ int sg[LH_];
  __shared__ float sS[4 * 44];
  __shared__ float sSf[44];
  int tid = threadIdx.x, b = blockIdx.x;
  if (tid < LH_) {
    float t = times[b * LH_ + tid];
    int mk = hmask[b * LH_ + tid];
    sg[tid] = mk ? groups[b * LH_ + tid] : -1;
    float pw = 1.f;
#pragma unroll
    for (int p = 0; p < 11; ++p) { sPow[tid * 11 + p] = pw; pw *= t; }
  }
  __syncthreads();
  int lane = tid & 63, w = tid >> 6;
  if (lane < 44) {
    int g = lane / 11, p = lane - 11 * g;
    float s = 0.f;
    for (int l = w * 50; l < w * 50 + 50; ++l) {
      if (sg[l] == g) s += sPow[l * 11 + p];
    }
    sS[w * 44 + lane] = s;
  }
  __syncthreads();
  if (tid < 44) sSf[tid] = sS[tid] + sS[44 + tid] + sS[88 + tid] + sS[132 + tid];
  __syncthreads();
  if (tid < 128) {
    float cnt = sSf[0] + sSf[11] + sSf[22] + sSf[33];
    float inv = 1.f / fmaxf(cnt, 1.f);
    float acc = 0.f;
#pragma unroll 4
    for (int q = 0; q < 44; ++q) acc += sSf[q] * CC[q * 128 + tid];
    FB[(size_t)b * 1408 + 384 + tid] = f2bf(acc * inv);
  }
}

// ---------------------------------------------------------------------------
// k_dln: fused dense GEMM (K=256) + bias + LN + silu -> FB[896:1408) bf16.
// 8 rows/block, grid 256. DIAGNOSTIC rep loop.
__global__ __launch_bounds__(256) void k_dln(
    const unsigned short* __restrict__ A, const unsigned short* __restrict__ BT,
    const float* __restrict__ dbias, const float* __restrict__ dg,
    const float* __restrict__ dbt, unsigned short* __restrict__ FB, int rep) {
  __shared__ float sS1[64], sS2[64];
  __shared__ float sMean[16], sRstd[16];
  int tid = threadIdx.x;
  int b0 = blockIdx.x * 8;
  int w = tid >> 6, lane = tid & 63;
  int m = lane & 15, quad = lane >> 4;
  int arow = b0 + m;
  if (arow > B_ - 1) arow = B_ - 1;
  const unsigned short* ap = A + (size_t)arow * 256 + quad * 8;
  for (int r0 = 0; r0 < rep; ++r0) {
    floatx4 acc[8];
#pragma unroll
    for (int nt = 0; nt < 8; ++nt) acc[nt] = {0.f, 0.f, 0.f, 0.f};
#pragma unroll
    for (int kc = 0; kc < 256; kc += 32) {
      short8v af = *(const short8v*)&ap[kc];
#pragma unroll
      for (int nt = 0; nt < 8; ++nt) {
        const unsigned short* bp = BT + (size_t)(w * 128 + nt * 16 + m) * 256 + quad * 8;
        short8v bf = *(const short8v*)&bp[kc];
        acc[nt] = __builtin_amdgcn_mfma_f32_16x16x32_bf16(af, bf, acc[nt], 0, 0, 0);
      }
    }
    float x[8][4];
    float bi[8], gj[8], tj[8];
#pragma unroll
    for (int nt = 0; nt < 8; ++nt) {
      int col = w * 128 + nt * 16 + m;
      bi[nt] = dbias[col];
    }
    float p1[4], p2[4];
#pragma unroll
    for (int r = 0; r < 4; ++r) { p1[r] = 0.f; p2[r] = 0.f; }
#pragma unroll
    for (int nt = 0; nt < 8; ++nt) {
#pragma unroll
      for (int r = 0; r < 4; ++r) {
        float v = acc[nt][r] + bi[nt];
        x[nt][r] = v;
        p1[r] += v;
        p2[r] += v * v;
      }
    }
#pragma unroll
    for (int r = 0; r < 4; ++r) {
#pragma unroll
      for (int off = 1; off < 16; off <<= 1) {
        p1[r] += __shfl_xor(p1[r], off, 64);
        p2[r] += __shfl_xor(p2[r], off, 64);
      }
      if (m == 0) {
        sS1[(quad * 4 + r) * 4 + w] = p1[r];
        sS2[(quad * 4 + r) * 4 + w] = p2[r];
      }
    }
    __syncthreads();
    if (tid < 16) {
      float s1 = sS1[tid * 4] + sS1[tid * 4 + 1] + sS1[tid * 4 + 2] + sS1[tid * 4 + 3];
      float s2 = sS2[tid * 4] + sS2[tid * 4 + 1] + sS2[tid * 4 + 2] + sS2[tid * 4 + 3];
      float mean = s1 / 512.f, var = s2 / 512.f - mean * mean;
      sMean[tid] = mean;
      sRstd[tid] = rsqrtf(var + 1e-5f);
    }
    __syncthreads();
#pragma unroll
    for (int nt = 0; nt < 8; ++nt) {
      int col = w * 128 + nt * 16 + m;
      gj[nt] = dg[col];
      tj[nt] = dbt[col];
    }
#pragma unroll
    for (int nt = 0; nt < 8; ++nt) {
      int col = w * 128 + nt * 16 + m;
#pragma unroll
      for (int r = 0; r < 4; ++r) {
        int row16 = quad * 4 + r;
        if (row16 < 8) {
          float y = siluf((x[nt][r] - sMean[row16]) * sRstd[row16] * gj[nt] + tj[nt]);
          FB[(size_t)(b0 + row16) * 1408 + 896 + col] = f2bf(y);
        }
      }
    }
    __syncthreads();
  }
}

// ---------------------------------------------------------------------------
// k_query: 8-row tile per block, K split across 4 waves, LDS reduce, LN+silu.
// grid 256. (NOT amplified this round.)
__global__ __launch_bounds__(256) void k_query_mfma(
    const unsigned short* __restrict__ FB, const unsigned short* __restrict__ QWBT,
    const float* __restrict__ qb, const float* __restrict__ qg,
    const float* __restrict__ qbt, float* __restrict__ query) {
  __shared__ float sP[4][16][128];  // 32 KB partial tiles
  int tid = threadIdx.x;
  int b0 = blockIdx.x * 8;
  int w = tid >> 6, lane = tid & 63;
  int m = lane & 15, quad = lane >> 4;
  int arow = b0 + m;
  if (arow > B_ - 1) arow = B_ - 1;
  const unsigned short* ap = FB + (size_t)arow * 1408 + quad * 8;
  const unsigned short* bp = QWBT + (size_t)m * 896 + quad * 8;
  floatx4 acc[8];
#pragma unroll
  for (int nt = 0; nt < 8; ++nt) acc[nt] = {0.f, 0.f, 0.f, 0.f};
#pragma unroll
  for (int ki = 0; ki < 7; ++ki) {
    int kc = w + ki * 4;
    int fo = (kc < 8) ? kc * 32 : (kc < 12 ? 384 + (kc - 8) * 32 : 896 + (kc - 12) * 32);
    short8v af = *(const short8v*)&ap[fo];
#pragma unroll
    for (int nt = 0; nt < 8; ++nt) {
      short8v bf = *(const short8v*)&bp[(size_t)nt * 16 * 896 + kc * 32];
      acc[nt] = __builtin_amdgcn_mfma_f32_16x16x32_bf16(af, bf, acc[nt], 0, 0, 0);
    }
  }
#pragma unroll
  for (int nt = 0; nt < 8; ++nt) {
#pragma unroll
    for (int r = 0; r < 4; ++r) {
      sP[w][quad * 4 + r][nt * 16 + m] = acc[nt][r];
    }
  }
  __syncthreads();
  int row = tid >> 4;
  if (row < 8) {
    int cb = (tid & 15) * 8;
    float x[8];
    float s1 = 0.f, s2 = 0.f;
#pragma unroll
    for (int j = 0; j < 8; ++j) {
      int c = cb + j;
      float v = sP[0][row][c] + sP[1][row][c] + sP[2][row][c] + sP[3][row][c] + qb[c];
      x[j] = v;
      s1 += v;
      s2 += v * v;
    }
#pragma unroll
    for (int off = 1; off < 16; off <<= 1) {
      s1 += __shfl_xor(s1, off, 64);
      s2 += __shfl_xor(s2, off, 64);
    }
    float mean = s1 * (1.f / 128.f);
    float var = s2 * (1.f / 128.f) - mean * mean;
    float rstd = rsqrtf(var + 1e-5f);
#pragma unroll
    for (int j = 0; j < 8; ++j) {
      int c = cb + j;
      query[(size_t)(b0 + row) * 128 + c] = siluf((x[j] - mean) * rstd * qg[c] + qbt[c]);
    }
  }
}

// ---------------------------------------------------------------------------
// single-pass online-softmax attention, compacted index list. grid B_, 256.
// (NOT amplified this round.)
__global__ __launch_bounds__(256) void k_attn4(
    const int* __restrict__ htok, const int* __restrict__ hpos,
    const int* __restrict__ hgrp, const int* __restrict__ hmask,
    const float* __restrict__ times,
    const float* __restrict__ tok_emb, const float* __restrict__ pos_emb,
    const float* __restrict__ grp_emb,
    const float* __restrict__ query, const float* __restrict__ E,
    unsigned short* __restrict__ FB) {
  __shared__ float sq[128];
  __shared__ float sE[5 * 128];
  __shared__ float sG[4 * 128];
  __shared__ float st[LH_];
  __shared__ float spoly[LH_];
  __shared__ int stok[LH_], spos[LH_], sgrp[LH_], smk[LH_];
  __shared__ int sidx[LH_];
  __shared__ int s_wcnt[4];
  __shared__ int s_nv;
  __shared__ float seq[5 * 2];
  __shared__ float s_eq[5];
  __shared__ float sA[16 * 128];
  __shared__ float sL[16];
  __shared__ float sM[16 * 5];
  int tid = threadIdx.x, b = blockIdx.x;
  int lane = tid & 63, w = tid >> 6;
  int rg = lane >> 4, li = lane & 15;
  int grp16 = w * 4 + rg;
  if (tid < 128) sq[tid] = query[b * 128 + tid];
  for (int idx = tid; idx < 5 * 128; idx += 256) sE[idx] = E[idx];
  for (int idx = tid; idx < 4 * 128; idx += 256) sG[idx] = grp_emb[idx];
  for (int l = tid; l < LH_; l += 256) {
    st[l] = times[b * LH_ + l];
    stok[l] = htok[b * LH_ + l];
    spos[l] = hpos[b * LH_ + l];
    sgrp[l] = hgrp[b * LH_ + l];
    smk[l] = hmask[b * LH_ + l];
  }
  __syncthreads();
  int cl = w * 64 + lane;
  int cvalid = (cl < LH_) ? smk[cl] : 0;
  unsigned long long cmb = __ballot(cvalid != 0);
  int cprefix = __popcll(cmb & ((1ull << lane) - 1ull));
  if (lane == 0) s_wcnt[w] = __popcll(cmb);
  if (tid < 128) {
    int wh = (tid >> 6) & 1;
#pragma unroll
    for (int p = 0; p < 5; ++p) {
      float v = sE[p * 128 + tid] * sq[tid];
      v = wredsum(v);
      if ((tid & 63) == 0) seq[p * 2 + wh] = v;
    }
  }
  __syncthreads();
  {
    int base = 0;
#pragma unroll
    for (int ww = 0; ww < 4; ++ww)
      if (ww < w) base += s_wcnt[ww];
    if (cvalid) sidx[base + cprefix] = cl;
    if (tid == 0) s_nv = s_wcnt[0] + s_wcnt[1] + s_wcnt[2] + s_wcnt[3];
  }
  if (tid < 5) s_eq[tid] = seq[tid * 2] + seq[tid * 2 + 1];
  __syncthreads();
  if (tid < LH_) {
    float t = st[tid];
    spoly[tid] = (((s_eq[4] * t + s_eq[3]) * t + s_eq[2]) * t + s_eq[1]) * t + s_eq[0];
  }
  __syncthreads();
  const float4 qa = *(const float4*)&sq[li * 8];
  const float4 qb4 = *(const float4*)&sq[li * 8 + 4];
  const float scale = 0.08838834764831845f;  // 1/sqrt(128)
  float a0 = 0.f, a1 = 0.f, a2 = 0.f, a3 = 0.f, a4 = 0.f, a5 = 0.f, a6 = 0.f, a7 = 0.f;
  float lsum = 0.f, mom1 = 0.f, mom2 = 0.f, mom3 = 0.f, mom4 = 0.f;
  int nv = s_nv;
  for (int i = grp16; i < nv; i += 16) {
    int l = sidx[i];
    int tok = stok[l], pos = spos[l], g = sgrp[l];
    const float* tp_ = &tok_emb[(size_t)tok * 128 + li * 8];
    const float* pp_ = &pos_emb[pos * 128 + li * 8];
    float4 ta = *(const float4*)tp_;
    float4 tb = *(const float4*)(tp_ + 4);
    float4 pa = *(const float4*)pp_;
    float4 pb = *(const float4*)(pp_ + 4);
    const float* gp_ = &sG[g * 128 + li * 8];
    float4 ga = *(const float4*)gp_;
    float4 gb = *(const float4*)(gp_ + 4);
    float v0 = ta.x + pa.x + ga.x, v1 = ta.y + pa.y + ga.y;
    float v2 = ta.z + pa.z + ga.z, v3 = ta.w + pa.w + ga.w;
    float v4 = tb.x + pb.x + gb.x, v5 = tb.y + pb.y + gb.y;
    float v6 = tb.z + pb.z + gb.z, v7 = tb.w + pb.w + gb.w;
    float d = v0 * qa.x + v1 * qa.y + v2 * qa.z + v3 * qa.w +
              v4 * qb4.x + v5 * qb4.y + v6 * qb4.z + v7 * qb4.w;
    d += __shfl_xor(d, 1, 64);
    d += __shfl_xor(d, 2, 64);
    d += __shfl_xor(d, 4, 64);
    d += __shfl_xor(d, 8, 64);
    float e = __expf((d + spoly[l]) * scale);
    float t = st[l];
    lsum += e;
    a0 += e * v0; a1 += e * v1; a2 += e * v2; a3 += e * v3;
    a4 += e * v4; a5 += e * v5; a6 += e * v6; a7 += e * v7;
    float tp = e * t;
    mom1 += tp; tp *= t;
    mom2 += tp; tp *= t;
    mom3 += tp; tp *= t;
    mom4 += tp;
  }
  float* ap2 = &sA[grp16 * 128 + li * 8];
  ap2[0] = a0; ap2[1] = a1; ap2[2] = a2; ap2[3] = a3;
  ap2[4] = a4; ap2[5] = a5; ap2[6] = a6; ap2[7] = a7;
  if (li == 0) {
    sL[grp16] = lsum;
    sM[grp16 * 5 + 1] = mom1; sM[grp16 * 5 + 2] = mom2;
    sM[grp16 * 5 + 3] = mom3; sM[grp16 * 5 + 4] = mom4;
  }
  __syncthreads();
  if (tid < 128) {
    int i = tid;
    float L = 0.f;
#pragma unroll
    for (int k = 0; k < 16; ++k) L += sL[k];
    float inv = 1.f / L;
    float v = 0.f;
#pragma unroll
    for (int k = 0; k < 16; ++k) v += sA[k * 128 + i];
    v *= inv;
    v += sE[i];
#pragma unroll
    for (int p = 1; p < 5; ++p) {
      float mp = 0.f;
#pragma unroll
      for (int k = 0; k < 16; ++k) mp += sM[k * 5 + p];
      v += mp * inv * sE[p * 128 + i];
    }
    unsigned short* row = FB + (size_t)b * 1408;
    float c = bf2f(row[i]), cm = bf2f(row[384 + i]);
    row[256 + i] = f2bf(v);
    row[512 + i] = f2bf(c * v);
    row[640 + i] = f2bf(c * cm);
    row[768 + i] = f2bf(fabsf(v - cm));
  }
}

// ---------------------------------------------------------------------------
// GEMM1: H1 = FB @ OW1BT^T. 16x128 tile, K split 4 waves, 2-deep pipeline.
// DIAGNOSTIC rep loop. grid 512.
__global__ __launch_bounds__(256) void k_gemm1(
    const unsigned short* __restrict__ A, const unsigned short* __restrict__ BT,
    float* __restrict__ H1, int rep) {
  __shared__ float sP[4][16][128];  // 32 KB partial tiles
  int tid = threadIdx.x;
  int bm = blockIdx.x >> 2;
  int bn = blockIdx.x & 3;
  int w = tid >> 6, lane = tid & 63;
  int m = lane & 15, quad = lane >> 4;
  const unsigned short* ap = A + (size_t)(bm * 16 + m) * 1408 + quad * 8;
  const unsigned short* bp = BT + (size_t)(bn * 128 + m) * 1408 + quad * 8;
  for (int r0 = 0; r0 < rep; ++r0) {
    floatx4 acc[8];
#pragma unroll
    for (int nt = 0; nt < 8; ++nt) acc[nt] = {0.f, 0.f, 0.f, 0.f};
    short8v afc = *(const short8v*)&ap[w * 32];
    short8v bfc[8];
#pragma unroll
    for (int nt = 0; nt < 8; ++nt)
      bfc[nt] = *(const short8v*)&bp[(size_t)nt * 16 * 1408 + w * 32];
#pragma unroll
    for (int ki = 0; ki < 11; ++ki) {
      short8v afn;
      short8v bfn[8];
      if (ki < 10) {
        int kc = w + (ki + 1) * 4;
        afn = *(const short8v*)&ap[kc * 32];
#pragma unroll
        for (int nt = 0; nt < 8; ++nt)
          bfn[nt] = *(const short8v*)&bp[(size_t)nt * 16 * 1408 + kc * 32];
      }
#pragma unroll
      for (int nt = 0; nt < 8; ++nt) {
        acc[nt] = __builtin_amdgcn_mfma_f32_16x16x32_bf16(afc, bfc[nt], acc[nt], 0, 0, 0);
      }
      if (ki < 10) {
        afc = afn;
#pragma unroll
        for (int nt = 0; nt < 8; ++nt) bfc[nt] = bfn[nt];
      }
    }
#pragma unroll
    for (int nt = 0; nt < 8; ++nt) {
#pragma unroll
      for (int r = 0; r < 4; ++r) {
        sP[w][quad * 4 + r][nt * 16 + m] = acc[nt][r];
      }
    }
    __syncthreads();
    int row = tid >> 4, cb = (tid & 15) * 8;
    float* hrow = H1 + (size_t)(bm * 16 + row) * 512 + bn * 128;
#pragma unroll
    for (int j = 0; j < 8; ++j) {
      int c = cb + j;
      hrow[c] = sP[0][row][c] + sP[1][row][c] + sP[2][row][c] + sP[3][row][c];
    }
    __syncthreads();
  }
}

// ---------------------------------------------------------------------------
// k_ep2: fused LN+silu(H1+ob1) -> bf16 LDS -> GEMM2 -> silu dot ow3 -> out.
// 8 rows/block, grid 256. DIAGNOSTIC rep loop.
__global__ __launch_bounds__(256) void k_ep2(
    const float* __restrict__ H1, const float* __restrict__ ob1,
    const float* __restrict__ og, const float* __restrict__ obt,
    const unsigned short* __restrict__ OW2BT, const float* __restrict__ ob2,
    const float* __restrict__ ow3, const float* __restrict__ ob3,
    float* __restrict__ out, int rep) {
  __shared__ short sB[16 * 520];
  __shared__ float sD[64];
  int tid = threadIdx.x;
  int b0 = blockIdx.x * 8;
  for (int r0 = 0; r0 < rep; ++r0) {
    {
      int g = tid >> 4, li = tid & 15;
      if (g < 8) {
        const float* hrow = H1 + (size_t)(b0 + g) * 512;
        float4 xv[8];
        float s1 = 0.f, s2 = 0.f;
#pragma unroll
        for (int k = 0; k < 8; ++k) {
          int col = li * 4 + k * 64;
          float4 v = *(const float4*)&hrow[col];
          float4 bb = *(const float4*)&ob1[col];
          v.x += bb.x; v.y += bb.y; v.z += bb.z; v.w += bb.w;
          xv[k] = v;
          s1 += v.x + v.y + v.z + v.w;
          s2 += v.x * v.x + v.y * v.y + v.z * v.z + v.w * v.w;
        }
#pragma unroll
        for (int off = 1; off < 16; off <<= 1) {
          s1 += __shfl_xor(s1, off, 64);
          s2 += __shfl_xor(s2, off, 64);
        }
        float mean = s1 * (1.f / 512.f);
        float var = s2 * (1.f / 512.f) - mean * mean;
        float rstd = rsqrtf(var + 1e-5f);
#pragma unroll
        for (int k = 0; k < 8; ++k) {
          int col = li * 4 + k * 64;
          float4 gg = *(const float4*)&og[col];
          float4 tt = *(const float4*)&obt[col];
          short4v pk;
          pk.x = (short)f2bf(siluf((xv[k].x - mean) * rstd * gg.x + tt.x));
          pk.y = (short)f2bf(siluf((xv[k].y - mean) * rstd * gg.y + tt.y));
          pk.z = (short)f2bf(siluf((xv[k].z - mean) * rstd * gg.z + tt.z));
          pk.w = (short)f2bf(siluf((xv[k].w - mean) * rstd * gg.w + tt.w));
          *(short4v*)((char*)sB + g * 1040 + li * 8 + k * 128) = pk;
        }
      } else {
        short4v z = {0, 0, 0, 0};
#pragma unroll
        for (int k = 0; k < 8; ++k) {
          *(short4v*)((char*)sB + g * 1040 + li * 8 + k * 128) = z;
        }
      }
    }
    __syncthreads();
    int w = tid >> 6, lane = tid & 63;
    int m = lane & 15, quad = lane >> 4;
    floatx4 acc[4];
#pragma unroll
    for (int nt = 0; nt < 4; ++nt) acc[nt] = {0.f, 0.f, 0.f, 0.f};
#pragma unroll
    for (int kc = 0; kc < 16; ++kc) {
      short8v af = *(const short8v*)((const char*)sB + m * 1040 + quad * 16 + kc * 64);
#pragma unroll
      for (int nt = 0; nt < 4; ++nt) {
        const unsigned short* bp = OW2BT + (size_t)(w * 64 + nt * 16 + m) * 512 + quad * 8;
        short8v bf = *(const short8v*)&bp[kc * 32];
        acc[nt] = __builtin_amdgcn_mfma_f32_16x16x32_bf16(af, bf, acc[nt], 0, 0, 0);
      }
    }
    float pz[4];
#pragma unroll
    for (int r = 0; r < 4; ++r) pz[r] = 0.f;
#pragma unroll
    for (int nt = 0; nt < 4; ++nt) {
      int col = w * 64 + nt * 16 + m;
      float c2 = ob2[col], w3 = ow3[col];
#pragma unroll
      for (int r = 0; r < 4; ++r) pz[r] += siluf(acc[nt][r] + c2) * w3;
    }
#pragma unroll
    for (int r = 0; r < 4; ++r) {
#pragma unroll
      for (int off = 1; off < 16; off <<= 1) pz[r] += __shfl_xor(pz[r], off, 64);
      if (m == 0) sD[(quad * 4 + r) * 4 + w] = pz[r];
    }
    __syncthreads();
    if (tid < 8) {
      out[b0 + tid] = sD[tid * 4] + sD[tid * 4 + 1] + sD[tid * 4 + 2] + sD[tid * 4 + 3] + ob3[0];
    }
    __syncthreads();
  }
}

// ---------------------------------------------------------------------------
extern "C" void kernel_launch(void* const* d_in, const int* in_sizes, int n_in,
                              void* d_out, int out_size, void* d_ws, size_t ws_size,
                              hipStream_t stream) {
  const int* cand_tok = (const int*)d_in[0];
  const int* ctx_tok = (const int*)d_in[1];
  const int* hist_tok = (const int*)d_in[2];
  const int* hist_pos = (const int*)d_in[3];
  const int* hist_grp = (const int*)d_in[4];
  const int* cand_mask = (const int*)d_in[5];
  const int* ctx_mask = (const int*)d_in[6];
  const int* hist_mask = (const int*)d_in[7];
  const float* hist_times = (const float*)d_in[8];
  const float* dense_feat = (const float*)d_in[9];
  const float* tok_emb = (const float*)d_in[10];
  const float* pos_emb = (const float*)d_in[11];
  const float* grp_emb = (const float*)d_in[12];
  const float* time_w1 = (const float*)d_in[13];
  const float* time_b1 = (const float*)d_in[14];
  const float* time_w2 = (const float*)d_in[15];
  const float* time_b2 = (const float*)d_in[16];
  const float* comp_w = (const float*)d_in[17];
  const float* comp_b = (const float*)d_in[18];
  const float* comp_g = (const float*)d_in[19];
  const float* comp_bt = (const float*)d_in[20];
  const float* dense_w = (const float*)d_in[21];
  const float* dense_b = (const float*)d_in[22];
  const float* dense_g = (const float*)d_in[23];
  const float* dense_bt = (const float*)d_in[24];
  const float* query_w = (const float*)d_in[25];
  const float* query_b = (const float*)d_in[26];
  const float* query_g = (const float*)d_in[27];
  const float* query_bt = (const float*)d_in[28];
  const float* out_w1 = (const float*)d_in[29];
  const float* out_b1 = (const float*)d_in[30];
  const float* out_g = (const float*)d_in[31];
  const float* out_bt = (const float*)d_in[32];
  const float* out_w2 = (const float*)d_in[33];
  const float* out_b2 = (const float*)d_in[34];
  const float* out_w3 = (const float*)d_in[35];
  const float* out_b3 = (const float*)d_in[36];
  float* out = (float*)d_out;

  // Workspace — validated 4,950,016-float footprint (round-0 layout).
  float* ws = (float*)d_ws;
  float* E = ws;                                     // 640
  float* CC = ws + 640;                              // 5632 (ends 6272)
  float* Fs = ws + 6272;                             // 640 (ends 6912)
  float* gvecs = ws + 6912;                          // 512 (ends 7424, pad 8192)
  float* query = ws + 8192;                          // 262144
  unsigned short* OW2BT = (unsigned short*)(ws + 1318912);   // 65536 fl
  unsigned short* QWBT = (unsigned short*)(ws + 1384448);    // 57344 fl
  unsigned short* DWBT = (unsigned short*)(ws + 1441792);    // 65536 fl
  unsigned short* DB = (unsigned short*)(ws + 1507328);      // 262144 fl
  float* H1 = ws + 2099200;                          // 1048576
  unsigned short* FB = (unsigned short*)(ws + 3147776);      // 1441792 fl
  unsigned short* OW1BT = (unsigned short*)(ws + 4589568);   // 360448 fl

  const int REP = 4;  // DIAGNOSTIC amplification #2 — the six unmeasured kernels

  k0ab<<<9, 256, 0, stream>>>(time_w1, time_b1, time_w2, time_b2,
                              grp_emb, comp_w, comp_b, E, Fs, gvecs, REP);
  k0c_fit<<<1, 512, 0, stream>>>(Fs, gvecs, comp_g, comp_bt, CC, REP);
  k_conv<<<3696, 256, 0, stream>>>(out_w1, out_w2, query_w, dense_w, dense_feat,
                                   OW1BT, OW2BT, QWBT, DWBT, DB, REP);
  k_candctx<<<B_, 256, 0, stream>>>(cand_tok, ctx_tok, cand_mask, ctx_mask,
                                    tok_emb, FB);
  k_comp_pow<<<B_, 256, 0, stream>>>(hist_times, hist_grp, hist_mask, CC, FB);
  k_dln<<<B_ / 8, 256, 0, stream>>>(DB, DWBT, dense_b, dense_g, dense_bt, FB, REP);
  k_query_mfma<<<B_ / 8, 256, 0, stream>>>(FB, QWBT, query_b, query_g, query_bt, query);
  k_attn4<<<B_, 256, 0, stream>>>(hist_tok, hist_pos, hist_grp, hist_mask, hist_times,
                                  tok_emb, pos_emb, grp_emb, query, E, FB);
  k_gemm1<<<512, 256, 0, stream>>>(FB, OW1BT, H1, REP);
  k_ep2<<<B_ / 8, 256, 0, stream>>>(H1, out_b1, out_g, out_bt,
                                    OW2BT, out_b2, out_w3, out_b3, out, REP);
}

// Round 12
// 270.007 us; speedup vs baseline: 1.3190x; 1.3190x over previous
//
#include <hip/hip_runtime.h>
#include <hip/hip_bf16.h>

#define B_ 2048
#define LC_ 20
#define LX_ 20
#define LH_ 200
#define D_ 128
#define H_ 512
#define DENSE_ 256

typedef __attribute__((ext_vector_type(8))) short short8v;
typedef __attribute__((ext_vector_type(4))) short short4v;
typedef __attribute__((ext_vector_type(4))) float floatx4;

__device__ __forceinline__ float siluf(float x) { return x / (1.f + __expf(-x)); }

__device__ __forceinline__ unsigned short f2bf(float f) {
  return __builtin_bit_cast(unsigned short, __float2bfloat16(f));
}
__device__ __forceinline__ float bf2f(unsigned short u) {
  return __bfloat162float(__builtin_bit_cast(__hip_bfloat16, u));
}

__device__ __forceinline__ float wredsum(float v) {
#pragma unroll
  for (int off = 32; off > 0; off >>= 1) v += __shfl_xor(v, off, 64);
  return v;
}

// pair index into the 15-entry upper-triangular (p<=q, 5x5) list
__device__ __forceinline__ int cidx(int a, int b) {
  if (a > b) { int t = a; a = b; b = t; }
  const int base[5] = {0, 5, 9, 12, 14};
  return base[a] + (b - a);
}

// ---------------------------------------------------------------------------
// k0ab: fused k0a+k0b. Blocks 0-4: E_p = c_p @ W2 (+b2 for p=0) then
// F_p = E_p @ comp_w[128:,:] (+comp_b for p=0). Blocks 5-8:
// gvec[g] = grp_emb[g] @ comp_w[:128,:].
__global__ __launch_bounds__(256) void k0ab(
    const float* __restrict__ w1, const float* __restrict__ b1,
    const float* __restrict__ W2, const float* __restrict__ b2,
    const float* __restrict__ grp_emb, const float* __restrict__ comp_w,
    const float* __restrict__ comp_b,
    float* __restrict__ E, float* __restrict__ F, float* __restrict__ gvec) {
  __shared__ float sc[128];
  __shared__ float spart[2][128];
  __shared__ float sE[128];
  int tid = threadIdx.x;
  int j = tid & 127, kh = tid >> 7;  // kh in {0,1}
  int blk = blockIdx.x;
  if (blk < 5) {
    if (tid < 128) {
      float w = w1[j], bb = b1[j];
      float y0 = siluf(bb);
      float y1 = siluf(0.25f * w + bb);
      float y2 = siluf(0.50f * w + bb);
      float y3 = siluf(0.75f * w + bb);
      float y4 = siluf(w + bb);
      float d1 = y1 - y0;
      float d2 = y2 - 2.f * y1 + y0;
      float d3 = y3 - 3.f * y2 + 3.f * y1 - y0;
      float d4 = y4 - 4.f * y3 + 6.f * y2 - 4.f * y1 + y0;
      float c0 = y0;
      float c1 = d1 - 0.5f * d2 + d3 * (1.f / 3.f) - 0.25f * d4;
      float c2 = 0.5f * d2 - 0.5f * d3 + (11.f / 24.f) * d4;
      float c3 = d3 * (1.f / 6.f) - 0.25f * d4;
      float c4 = d4 * (1.f / 24.f);
      float cp;
      int p = blk;
      if (p == 0) cp = c0;
      else if (p == 1) cp = c1 * 4.f;
      else if (p == 2) cp = c2 * 16.f;
      else if (p == 3) cp = c3 * 64.f;
      else cp = c4 * 256.f;
      sc[j] = cp;
    }
    __syncthreads();
    float acc = 0.f;
#pragma unroll 8
    for (int kk = kh * 64; kk < kh * 64 + 64; ++kk) acc += sc[kk] * W2[kk * 128 + j];
    spart[kh][j] = acc;
    __syncthreads();
    if (tid < 128) {
      float e = spart[0][j] + spart[1][j];
      if (blk == 0) e += b2[j];
      E[blk * 128 + j] = e;
      sE[j] = e;
    }
    __syncthreads();
    acc = 0.f;
#pragma unroll 8
    for (int kk = kh * 64; kk < kh * 64 + 64; ++kk)
      acc += sE[kk] * comp_w[(128 + kk) * 128 + j];
    spart[kh][j] = acc;
    __syncthreads();
    if (tid < 128) {
      float f = spart[0][j] + spart[1][j];
      if (blk == 0) f += comp_b[j];
      F[blk * 128 + j] = f;
    }
  } else {
    int g = blk - 5;
    if (tid < 128) sc[j] = grp_emb[g * 128 + j];
    __syncthreads();
    float acc = 0.f;
#pragma unroll 8
    for (int kk = kh * 64; kk < kh * 64 + 64; ++kk)
      acc += sc[kk] * comp_w[kk * 128 + j];
    spart[kh][j] = acc;
    __syncthreads();
    if (tid < 128) gvec[g * 128 + j] = spart[0][j] + spart[1][j];
  }
}

// ---------------------------------------------------------------------------
// k0c: 48 channel-moments + analytic LN moment polys + 512 degree-10
// Chebyshev fits -> CC. 1 block, 512 threads.
__global__ __launch_bounds__(512) void k0c_fit(
    const float* __restrict__ F, const float* __restrict__ gvec,
    const float* __restrict__ cg_, const float* __restrict__ cbt_,
    float* __restrict__ CC) {
  __shared__ float sF2[640];
  __shared__ float sGv[512];
  __shared__ float s48[48];
  __shared__ float sMC[20], sVC[36];
  int tid = threadIdx.x;
  for (int idx = tid; idx < 640; idx += 512) sF2[idx] = F[idx];
  if (tid < 512) sGv[tid] = gvec[tid];
  __syncthreads();
  int wv = tid >> 6, lane = tid & 63;
#pragma unroll
  for (int i = 0; i < 6; ++i) {
    int m = wv * 6 + i;
    if (m < 48) {
      const float* va;
      const float* vb = nullptr;
      int t = m;
      if (t < 5) va = &sF2[t * 128];
      else if (t < 9) va = &sGv[(t - 5) * 128];
      else if (t < 13) { va = &sGv[(t - 9) * 128]; vb = va; }
      else if (t < 33) {
        int g = (t - 13) / 5, p = (t - 13) % 5;
        va = &sGv[g * 128]; vb = &sF2[p * 128];
      } else {
        int idx = t - 33;
        int a = 0;
        if (idx >= 14) a = 4;
        else if (idx >= 12) a = 3;
        else if (idx >= 9) a = 2;
        else if (idx >= 5) a = 1;
        const int base[5] = {0, 5, 9, 12, 14};
        int bcol = a + (idx - base[a]);
        va = &sF2[a * 128]; vb = &sF2[bcol * 128];
      }
      float s;
      if (vb) s = va[lane] * vb[lane] + va[lane + 64] * vb[lane + 64];
      else    s = va[lane] + va[lane + 64];
      s = wredsum(s);
      if (lane == 0) s48[m] = s * (1.f / 128.f);
    }
  }
  __syncthreads();
  if (tid < 20) {
    int g = tid / 5, p = tid % 5;
    sMC[g * 5 + p] = s48[p] + (p == 0 ? s48[5 + g] : 0.f);
  }
  if (tid < 36) {
    int g = tid / 9, kk = tid % 9;
    float v = (kk == 0 ? s48[9 + g] : 0.f);
    if (kk < 5) v += 2.f * s48[13 + g * 5 + kk];
#pragma unroll
    for (int p = 0; p < 5; ++p) {
      int q = kk - p;
      if (q >= 0 && q <= 4) v += s48[33 + cidx(p, q)];
    }
    sVC[g * 9 + kk] = v;
  }
  __syncthreads();
  const float nodes[11] = {0.f, 0.02447174185f, 0.09549150281f, 0.2061073739f,
                           0.3454915028f, 0.5f, 0.6545084972f, 0.7938926261f,
                           0.9045084972f, 0.9755282581f, 1.f};
  int g = tid >> 7, j = tid & 127;
  float cgj = cg_[j], btj = cbt_[j];
  float F0 = sF2[j], F1 = sF2[128 + j], F2v = sF2[256 + j], F3 = sF2[384 + j], F4 = sF2[512 + j];
  const float* mc = &sMC[g * 5];
  const float* vc = &sVC[g * 9];
  float gv = sGv[g * 128 + j];
  float fv[11];
#pragma unroll
  for (int n = 0; n < 11; ++n) {
    float t = nodes[n];
    float mean = (((mc[4] * t + mc[3]) * t + mc[2]) * t + mc[1]) * t + mc[0];
    float e2 = vc[8];
#pragma unroll
    for (int p = 7; p >= 0; --p) e2 = e2 * t + vc[p];
    float rstd = rsqrtf(e2 - mean * mean + 1e-5f);
    float pre = gv + ((((F4 * t + F3) * t + F2v) * t + F1) * t + F0);
    fv[n] = siluf((pre - mean) * rstd * cgj + btj);
  }
#pragma unroll
  for (int ord = 1; ord <= 10; ++ord) {
#pragma unroll
    for (int n = 10; n >= 1; --n) {
      if (n >= ord) fv[n] = (fv[n] - fv[n - 1]) / (nodes[n] - nodes[n - ord]);
    }
  }
  float c[11];
#pragma unroll
  for (int i = 0; i < 11; ++i) c[i] = 0.f;
  c[0] = fv[10];
#pragma unroll
  for (int n = 9; n >= 0; --n) {
    int deg = 9 - n;
    float x = nodes[n];
    c[deg + 1] = c[deg];
#pragma unroll
    for (int i = 10; i >= 1; --i) {
      if (i <= deg) c[i] = c[i - 1] - x * c[i];
    }
    c[0] = fv[n] - x * c[0];
  }
#pragma unroll
  for (int p = 0; p < 11; ++p) CC[(g * 11 + p) * 128 + j] = c[p];
}

// ---------------------------------------------------------------------------
// k_conv: blocks 0..175 -> out_w1 transpose; blocks 176..3695 -> misc convs.
__global__ __launch_bounds__(256) void k_conv(
    const float* __restrict__ ow1, const float* __restrict__ ow2,
    const float* __restrict__ qw, const float* __restrict__ dw,
    const float* __restrict__ df,
    unsigned short* __restrict__ OW1BT, unsigned short* __restrict__ OW2BT,
    unsigned short* __restrict__ QWBT, unsigned short* __restrict__ DWBT,
    unsigned short* __restrict__ DB) {
  __shared__ float tile[64][65];
  int tid = threadIdx.x;
  if (blockIdx.x < 176) {
    int bk = blockIdx.x % 22;
    int bn = blockIdx.x / 22;
    int tx = tid & 63, ty = tid >> 6;
#pragma unroll
    for (int r = 0; r < 16; ++r) {
      int kl = ty * 16 + r;
      tile[kl][tx] = ow1[(size_t)(bk * 64 + kl) * 512 + bn * 64 + tx];
    }
    __syncthreads();
#pragma unroll
    for (int r = 0; r < 16; ++r) {
      int nl = ty * 16 + r;
      OW1BT[(size_t)(bn * 64 + nl) * 1408 + bk * 64 + tx] = f2bf(tile[tx][nl]);
    }
  } else {
    int idx = (blockIdx.x - 176) * 256 + tid;
    if (idx < 131072) {
      int n = idx >> 9, k = idx & 511;
      OW2BT[(size_t)n * 512 + k] = f2bf(ow2[(size_t)k * 256 + n]);
    } else if (idx < 245760) {
      int i = idx - 131072;
      int n = i / 896, k = i - n * 896;
      QWBT[(size_t)n * 896 + k] = f2bf(qw[(size_t)k * 128 + n]);
    } else if (idx < 376832) {
      int i = idx - 245760;
      int n = i >> 8, k = i & 255;
      DWBT[(size_t)n * 256 + k] = f2bf(dw[(size_t)k * 512 + n]);
    } else {
      int i = idx - 376832;
      DB[i] = f2bf(df[i]);
    }
  }
}

// ---------------------------------------------------------------------------
// cand_s / ctx_s masked means -> FB[0:256) bf16, ballot-compacted.
// grid B_, block 256.
__global__ __launch_bounds__(256) void k_candctx(
    const int* __restrict__ ctok, const int* __restrict__ xtok,
    const int* __restrict__ cmask, const int* __restrict__ xmask,
    const float* __restrict__ tok_emb, unsigned short* __restrict__ FB) {
  __shared__ int sLc[LC_], sLx[LX_];
  __shared__ int scnt[2];
  int b = blockIdx.x, tid = threadIdx.x;
  int w = tid >> 6, lane = tid & 63;
  if (w == 0) {
    int valid = 0, tok = 0;
    if (lane < LC_) {
      valid = cmask[b * LC_ + lane];
      tok = ctok[b * LC_ + lane];
    }
    unsigned long long mb = __ballot(valid != 0);
    int prefix = __popcll(mb & ((1ull << lane) - 1ull));
    if (valid) sLc[prefix] = tok;
    if (lane == 0) scnt[0] = __popcll(mb);
  } else if (w == 1) {
    int valid = 0, tok = 0;
    if (lane < LX_) {
      valid = xmask[b * LX_ + lane];
      tok = xtok[b * LX_ + lane];
    }
    unsigned long long mb = __ballot(valid != 0);
    int prefix = __popcll(mb & ((1ull << lane) - 1ull));
    if (valid) sLx[prefix] = tok;
    if (lane == 0) scnt[1] = __popcll(mb);
  }
  __syncthreads();
  int j = tid & 127, half = tid >> 7;
  float acc = 0.f;
  if (half == 0) {
    int n = scnt[0];
    for (int i = 0; i < n; ++i) acc += tok_emb[(size_t)sLc[i] * 128 + j];
    FB[(size_t)b * 1408 + j] = f2bf(acc / fmaxf((float)n, 1.f));
  } else {
    int n = scnt[1];
    for (int i = 0; i < n; ++i) acc += tok_emb[(size_t)sLx[i] * 128 + j];
    FB[(size_t)b * 1408 + 128 + j] = f2bf(acc / fmaxf((float)n, 1.f));
  }
}

// ---------------------------------------------------------------------------
// comp summary via per-(g,p) power sums + precomputed poly CC. grid B_, 256
__global__ __launch_bounds__(256) void k_comp_pow(
    const float* __restrict__ times, const int* __restrict__ groups,
    const int* __restrict__ hmask, const float* __restrict__ CC,
    unsigned short* __restrict__ FB) {
  __shared__ float sPow[LH_ * 11];
  __shared__ int sg[LH_];
  __shared__ float sS[4 * 44];
  __shared__ float sSf[44];
  int tid = threadIdx.x, b = blockIdx.x;
  if (tid < LH_) {
    float t = times[b * LH_ + tid];
    int mk = hmask[b * LH_ + tid];
    sg[tid] = mk ? groups[b * LH_ + tid] : -1;
    float pw = 1.f;
#pragma unroll
    for (int p = 0; p < 11; ++p) { sPow[tid * 11 + p] = pw; pw *= t; }
  }
  __syncthreads();
  int lane = tid & 63, w = tid >> 6;
  if (lane < 44) {
    int g = lane / 11, p = lane - 11 * g;
    float s = 0.f;
    for (int l = w * 50; l < w * 50 + 50; ++l) {
      if (sg[l] == g) s += sPow[l * 11 + p];
    }
    sS[w * 44 + lane] = s;
  }
  __syncthreads();
  if (tid < 44) sSf[tid] = sS[tid] + sS[44 + tid] + sS[88 + tid] + sS[132 + tid];
  __syncthreads();
  if (tid < 128) {
    float cnt = sSf[0] + sSf[11] + sSf[22] + sSf[33];
    float inv = 1.f / fmaxf(cnt, 1.f);
    float acc = 0.f;
#pragma unroll 4
    for (int q = 0; q < 44; ++q) acc += sSf[q] * CC[q * 128 + tid];
    FB[(size_t)b * 1408 + 384 + tid] = f2bf(acc * inv);
  }
}

// ---------------------------------------------------------------------------
// k_dln: fused dense GEMM (DB @ DWBT^T, K=256) + bias + LN + silu -> FB[896:1408)
// bf16. 8 rows/block (MFMA computes 16, top 8 discarded), grid 256, block 256.
__global__ __launch_bounds__(256) void k_dln(
    const unsigned short* __restrict__ A, const unsigned short* __restrict__ BT,
    const float* __restrict__ dbias, const float* __restrict__ dg,
    const float* __restrict__ dbt, unsigned short* __restrict__ FB) {
  __shared__ float sS1[64], sS2[64];
  __shared__ float sMean[16], sRstd[16];
  int tid = threadIdx.x;
  int b0 = blockIdx.x * 8;
  int w = tid >> 6, lane = tid & 63;
  int m = lane & 15, quad = lane >> 4;
  int arow = b0 + m;
  if (arow > B_ - 1) arow = B_ - 1;
  const unsigned short* ap = A + (size_t)arow * 256 + quad * 8;
  floatx4 acc[8];
#pragma unroll
  for (int nt = 0; nt < 8; ++nt) acc[nt] = {0.f, 0.f, 0.f, 0.f};
#pragma unroll
  for (int kc = 0; kc < 256; kc += 32) {
    short8v af = *(const short8v*)&ap[kc];
#pragma unroll
    for (int nt = 0; nt < 8; ++nt) {
      const unsigned short* bp = BT + (size_t)(w * 128 + nt * 16 + m) * 256 + quad * 8;
      short8v bf = *(const short8v*)&bp[kc];
      acc[nt] = __builtin_amdgcn_mfma_f32_16x16x32_bf16(af, bf, acc[nt], 0, 0, 0);
    }
  }
  float x[8][4];
  float bi[8], gj[8], tj[8];
#pragma unroll
  for (int nt = 0; nt < 8; ++nt) {
    int col = w * 128 + nt * 16 + m;
    bi[nt] = dbias[col];
  }
  float p1[4], p2[4];
#pragma unroll
  for (int r = 0; r < 4; ++r) { p1[r] = 0.f; p2[r] = 0.f; }
#pragma unroll
  for (int nt = 0; nt < 8; ++nt) {
#pragma unroll
    for (int r = 0; r < 4; ++r) {
      float v = acc[nt][r] + bi[nt];
      x[nt][r] = v;
      p1[r] += v;
      p2[r] += v * v;
    }
  }
#pragma unroll
  for (int r = 0; r < 4; ++r) {
#pragma unroll
    for (int off = 1; off < 16; off <<= 1) {
      p1[r] += __shfl_xor(p1[r], off, 64);
      p2[r] += __shfl_xor(p2[r], off, 64);
    }
    if (m == 0) {
      sS1[(quad * 4 + r) * 4 + w] = p1[r];
      sS2[(quad * 4 + r) * 4 + w] = p2[r];
    }
  }
  __syncthreads();
  if (tid < 16) {
    float s1 = sS1[tid * 4] + sS1[tid * 4 + 1] + sS1[tid * 4 + 2] + sS1[tid * 4 + 3];
    float s2 = sS2[tid * 4] + sS2[tid * 4 + 1] + sS2[tid * 4 + 2] + sS2[tid * 4 + 3];
    float mean = s1 / 512.f, var = s2 / 512.f - mean * mean;
    sMean[tid] = mean;
    sRstd[tid] = rsqrtf(var + 1e-5f);
  }
  __syncthreads();
#pragma unroll
  for (int nt = 0; nt < 8; ++nt) {
    int col = w * 128 + nt * 16 + m;
    gj[nt] = dg[col];
    tj[nt] = dbt[col];
  }
#pragma unroll
  for (int nt = 0; nt < 8; ++nt) {
    int col = w * 128 + nt * 16 + m;
#pragma unroll
    for (int r = 0; r < 4; ++r) {
      int row16 = quad * 4 + r;
      if (row16 < 8) {
        float y = siluf((x[nt][r] - sMean[row16]) * sRstd[row16] * gj[nt] + tj[nt]);
        FB[(size_t)(b0 + row16) * 1408 + 896 + col] = f2bf(y);
      }
    }
  }
}

// ---------------------------------------------------------------------------
// k_query: 8-row tile per block (MFMA computes 16, top 8 discarded), K=1408
// split across 4 waves (7 of 28 K-steps each), LDS partial reduce, fused
// LN+silu epilogue. grid 256, block 256.
__global__ __launch_bounds__(256) void k_query_mfma(
    const unsigned short* __restrict__ FB, const unsigned short* __restrict__ QWBT,
    const float* __restrict__ qb, const float* __restrict__ qg,
    const float* __restrict__ qbt, float* __restrict__ query) {
  __shared__ float sP[4][16][128];  // 32 KB partial tiles
  int tid = threadIdx.x;
  int b0 = blockIdx.x * 8;
  int w = tid >> 6, lane = tid & 63;
  int m = lane & 15, quad = lane >> 4;
  int arow = b0 + m;
  if (arow > B_ - 1) arow = B_ - 1;
  const unsigned short* ap = FB + (size_t)arow * 1408 + quad * 8;
  const unsigned short* bp = QWBT + (size_t)m * 896 + quad * 8;
  floatx4 acc[8];
#pragma unroll
  for (int nt = 0; nt < 8; ++nt) acc[nt] = {0.f, 0.f, 0.f, 0.f};
#pragma unroll
  for (int ki = 0; ki < 7; ++ki) {
    int kc = w + ki * 4;
    int fo = (kc < 8) ? kc * 32 : (kc < 12 ? 384 + (kc - 8) * 32 : 896 + (kc - 12) * 32);
    short8v af = *(const short8v*)&ap[fo];
#pragma unroll
    for (int nt = 0; nt < 8; ++nt) {
      short8v bf = *(const short8v*)&bp[(size_t)nt * 16 * 896 + kc * 32];
      acc[nt] = __builtin_amdgcn_mfma_f32_16x16x32_bf16(af, bf, acc[nt], 0, 0, 0);
    }
  }
#pragma unroll
  for (int nt = 0; nt < 8; ++nt) {
#pragma unroll
    for (int r = 0; r < 4; ++r) {
      sP[w][quad * 4 + r][nt * 16 + m] = acc[nt][r];
    }
  }
  __syncthreads();
  // epilogue: rows 0..7 only (tid<128 -> waves 0,1, wave-uniform branch)
  int row = tid >> 4;
  if (row < 8) {
    int cb = (tid & 15) * 8;
    float x[8];
    float s1 = 0.f, s2 = 0.f;
#pragma unroll
    for (int j = 0; j < 8; ++j) {
      int c = cb + j;
      float v = sP[0][row][c] + sP[1][row][c] + sP[2][row][c] + sP[3][row][c] + qb[c];
      x[j] = v;
      s1 += v;
      s2 += v * v;
    }
#pragma unroll
    for (int off = 1; off < 16; off <<= 1) {
      s1 += __shfl_xor(s1, off, 64);
      s2 += __shfl_xor(s2, off, 64);
    }
    float mean = s1 * (1.f / 128.f);
    float var = s2 * (1.f / 128.f) - mean * mean;
    float rstd = rsqrtf(var + 1e-5f);
#pragma unroll
    for (int j = 0; j < 8; ++j) {
      int c = cb + j;
      query[(size_t)(b0 + row) * 128 + c] = siluf((x[j] - mean) * rstd * qg[c] + qbt[c]);
    }
  }
}

// ---------------------------------------------------------------------------
// single-pass online-softmax attention, 16-lane rows (4 rows/wave concurrent),
// dwordx4 gathers, staged poly term, ballot-compacted valid-index list (dense
// uniform gather loop, no exec-mask waste). grid B_, block 256.
__global__ __launch_bounds__(256) void k_attn4(
    const int* __restrict__ htok, const int* __restrict__ hpos,
    const int* __restrict__ hgrp, const int* __restrict__ hmask,
    const float* __restrict__ times,
    const float* __restrict__ tok_emb, const float* __restrict__ pos_emb,
    const float* __restrict__ grp_emb,
    const float* __restrict__ query, const float* __restrict__ E,
    unsigned short* __restrict__ FB) {
  __shared__ float sq[128];
  __shared__ float sE[5 * 128];
  __shared__ float sG[4 * 128];
  __shared__ float st[LH_];
  __shared__ float spoly[LH_];
  __shared__ int stok[LH_], spos[LH_], sgrp[LH_], smk[LH_];
  __shared__ int sidx[LH_];
  __shared__ int s_wcnt[4];
  __shared__ int s_nv;
  __shared__ float seq[5 * 2];
  __shared__ float s_eq[5];
  __shared__ float sA[16 * 128];
  __shared__ float sL[16];
  __shared__ float sM[16 * 5];
  int tid = threadIdx.x, b = blockIdx.x;
  int lane = tid & 63, w = tid >> 6;
  int rg = lane >> 4, li = lane & 15;
  int grp16 = w * 4 + rg;
  if (tid < 128) sq[tid] = query[b * 128 + tid];
  for (int idx = tid; idx < 5 * 128; idx += 256) sE[idx] = E[idx];
  for (int idx = tid; idx < 4 * 128; idx += 256) sG[idx] = grp_emb[idx];
  for (int l = tid; l < LH_; l += 256) {
    st[l] = times[b * LH_ + l];
    stok[l] = htok[b * LH_ + l];
    spos[l] = hpos[b * LH_ + l];
    sgrp[l] = hgrp[b * LH_ + l];
    smk[l] = hmask[b * LH_ + l];
  }
  __syncthreads();
  // ---- compaction step 1: per-wave ballot counts (wave w owns l = w*64+lane)
  int cl = w * 64 + lane;
  int cvalid = (cl < LH_) ? smk[cl] : 0;
  unsigned long long cmb = __ballot(cvalid != 0);
  int cprefix = __popcll(cmb & ((1ull << lane) - 1ull));
  if (lane == 0) s_wcnt[w] = __popcll(cmb);
  // ---- E.q dots (waves 0,1) run in the same phase
  if (tid < 128) {
    int wh = (tid >> 6) & 1;
#pragma unroll
    for (int p = 0; p < 5; ++p) {
      float v = sE[p * 128 + tid] * sq[tid];
      v = wredsum(v);
      if ((tid & 63) == 0) seq[p * 2 + wh] = v;
    }
  }
  __syncthreads();
  // ---- compaction step 2: scatter valid l's to dense sidx
  {
    int base = 0;
#pragma unroll
    for (int ww = 0; ww < 4; ++ww)
      if (ww < w) base += s_wcnt[ww];
    if (cvalid) sidx[base + cprefix] = cl;
    if (tid == 0) s_nv = s_wcnt[0] + s_wcnt[1] + s_wcnt[2] + s_wcnt[3];
  }
  if (tid < 5) s_eq[tid] = seq[tid * 2] + seq[tid * 2 + 1];
  __syncthreads();
  if (tid < LH_) {
    float t = st[tid];
    spoly[tid] = (((s_eq[4] * t + s_eq[3]) * t + s_eq[2]) * t + s_eq[1]) * t + s_eq[0];
  }
  __syncthreads();
  const float4 qa = *(const float4*)&sq[li * 8];
  const float4 qb4 = *(const float4*)&sq[li * 8 + 4];
  const float scale = 0.08838834764831845f;  // 1/sqrt(128)
  float a0 = 0.f, a1 = 0.f, a2 = 0.f, a3 = 0.f, a4 = 0.f, a5 = 0.f, a6 = 0.f, a7 = 0.f;
  float lsum = 0.f, mom1 = 0.f, mom2 = 0.f, mom3 = 0.f, mom4 = 0.f;
  int nv = s_nv;
  for (int i = grp16; i < nv; i += 16) {
    int l = sidx[i];
    int tok = stok[l], pos = spos[l], g = sgrp[l];
    const float* tp_ = &tok_emb[(size_t)tok * 128 + li * 8];
    const float* pp_ = &pos_emb[pos * 128 + li * 8];
    float4 ta = *(const float4*)tp_;
    float4 tb = *(const float4*)(tp_ + 4);
    float4 pa = *(const float4*)pp_;
    float4 pb = *(const float4*)(pp_ + 4);
    const float* gp_ = &sG[g * 128 + li * 8];
    float4 ga = *(const float4*)gp_;
    float4 gb = *(const float4*)(gp_ + 4);
    float v0 = ta.x + pa.x + ga.x, v1 = ta.y + pa.y + ga.y;
    float v2 = ta.z + pa.z + ga.z, v3 = ta.w + pa.w + ga.w;
    float v4 = tb.x + pb.x + gb.x, v5 = tb.y + pb.y + gb.y;
    float v6 = tb.z + pb.z + gb.z, v7 = tb.w + pb.w + gb.w;
    float d = v0 * qa.x + v1 * qa.y + v2 * qa.z + v3 * qa.w +
              v4 * qb4.x + v5 * qb4.y + v6 * qb4.z + v7 * qb4.w;
    d += __shfl_xor(d, 1, 64);
    d += __shfl_xor(d, 2, 64);
    d += __shfl_xor(d, 4, 64);
    d += __shfl_xor(d, 8, 64);
    float e = __expf((d + spoly[l]) * scale);
    float t = st[l];
    lsum += e;
    a0 += e * v0; a1 += e * v1; a2 += e * v2; a3 += e * v3;
    a4 += e * v4; a5 += e * v5; a6 += e * v6; a7 += e * v7;
    float tp = e * t;
    mom1 += tp; tp *= t;
    mom2 += tp; tp *= t;
    mom3 += tp; tp *= t;
    mom4 += tp;
  }
  float* ap2 = &sA[grp16 * 128 + li * 8];
  ap2[0] = a0; ap2[1] = a1; ap2[2] = a2; ap2[3] = a3;
  ap2[4] = a4; ap2[5] = a5; ap2[6] = a6; ap2[7] = a7;
  if (li == 0) {
    sL[grp16] = lsum;
    sM[grp16 * 5 + 1] = mom1; sM[grp16 * 5 + 2] = mom2;
    sM[grp16 * 5 + 3] = mom3; sM[grp16 * 5 + 4] = mom4;
  }
  __syncthreads();
  if (tid < 128) {
    int i = tid;
    float L = 0.f;
#pragma unroll
    for (int k = 0; k < 16; ++k) L += sL[k];
    float inv = 1.f / L;
    float v = 0.f;
#pragma unroll
    for (int k = 0; k < 16; ++k) v += sA[k * 128 + i];
    v *= inv;
    v += sE[i];
#pragma unroll
    for (int p = 1; p < 5; ++p) {
      float mp = 0.f;
#pragma unroll
      for (int k = 0; k < 16; ++k) mp += sM[k * 5 + p];
      v += mp * inv * sE[p * 128 + i];
    }
    unsigned short* row = FB + (size_t)b * 1408;
    float c = bf2f(row[i]), cm = bf2f(row[384 + i]);
    row[256 + i] = f2bf(v);
    row[512 + i] = f2bf(c * v);
    row[640 + i] = f2bf(c * cm);
    row[768 + i] = f2bf(fabsf(v - cm));
  }
}

// ---------------------------------------------------------------------------
// GEMM1 via bf16 MFMA: H1[2048x512] = FB @ OW1BT^T. Block = 16 rows x 128
// cols; K=1408 split across 4 waves (11 of 44 K-steps each, stride-4).
// Manual 2-deep register pipeline; LDS partial reduce.
// grid 512 (bm 0..127 x bn 0..3), block 256.
__global__ __launch_bounds__(256) void k_gemm1(
    const unsigned short* __restrict__ A, const unsigned short* __restrict__ BT,
    float* __restrict__ H1) {
  __shared__ float sP[4][16][128];  // 32 KB partial tiles
  int tid = threadIdx.x;
  int bm = blockIdx.x >> 2;
  int bn = blockIdx.x & 3;
  int w = tid >> 6, lane = tid & 63;
  int m = lane & 15, quad = lane >> 4;
  const unsigned short* ap = A + (size_t)(bm * 16 + m) * 1408 + quad * 8;
  const unsigned short* bp = BT + (size_t)(bn * 128 + m) * 1408 + quad * 8;
  floatx4 acc[8];
#pragma unroll
  for (int nt = 0; nt < 8; ++nt) acc[nt] = {0.f, 0.f, 0.f, 0.f};
  // prologue: load step 0 (kc = w)
  short8v afc = *(const short8v*)&ap[w * 32];
  short8v bfc[8];
#pragma unroll
  for (int nt = 0; nt < 8; ++nt)
    bfc[nt] = *(const short8v*)&bp[(size_t)nt * 16 * 1408 + w * 32];
#pragma unroll
  for (int ki = 0; ki < 11; ++ki) {
    short8v afn;
    short8v bfn[8];
    if (ki < 10) {
      int kc = w + (ki + 1) * 4;
      afn = *(const short8v*)&ap[kc * 32];
#pragma unroll
      for (int nt = 0; nt < 8; ++nt)
        bfn[nt] = *(const short8v*)&bp[(size_t)nt * 16 * 1408 + kc * 32];
    }
#pragma unroll
    for (int nt = 0; nt < 8; ++nt) {
      acc[nt] = __builtin_amdgcn_mfma_f32_16x16x32_bf16(afc, bfc[nt], acc[nt], 0, 0, 0);
    }
    if (ki < 10) {
      afc = afn;
#pragma unroll
      for (int nt = 0; nt < 8; ++nt) bfc[nt] = bfn[nt];
    }
  }
#pragma unroll
  for (int nt = 0; nt < 8; ++nt) {
#pragma unroll
    for (int r = 0; r < 4; ++r) {
      sP[w][quad * 4 + r][nt * 16 + m] = acc[nt][r];
    }
  }
  __syncthreads();
  // epilogue: 16 threads per row, 8 cols each; sum 4 partials, write f32
  int row = tid >> 4, cb = (tid & 15) * 8;
  float* hrow = H1 + (size_t)(bm * 16 + row) * 512 + bn * 128;
#pragma unroll
  for (int j = 0; j < 8; ++j) {
    int c = cb + j;
    hrow[c] = sP[0][row][c] + sP[1][row][c] + sP[2][row][c] + sP[3][row][c];
  }
}

// ---------------------------------------------------------------------------
// k_ep2: fused LN+silu(H1+ob1) -> bf16 LDS tile -> GEMM2 (K=512 = LN axis)
// -> silu(+ob2) dot ow3 -> out. 8 rows/block (sB rows 8-15 zeroed), grid 256.
__global__ __launch_bounds__(256) void k_ep2(
    const float* __restrict__ H1, const float* __restrict__ ob1,
    const float* __restrict__ og, const float* __restrict__ obt,
    const unsigned short* __restrict__ OW2BT, const float* __restrict__ ob2,
    const float* __restrict__ ow3, const float* __restrict__ ob3,
    float* __restrict__ out) {
  __shared__ short sB[16 * 520];  // 16 rows x 512 bf16, row stride 520 (bank spread)
  __shared__ float sD[64];
  int tid = threadIdx.x;
  int b0 = blockIdx.x * 8;
  // ---- phase 1: LN+silu rows 0..7 of H1 -> sB; rows 8..15 zero-filled.
  {
    int g = tid >> 4, li = tid & 15;
    if (g < 8) {
      const float* hrow = H1 + (size_t)(b0 + g) * 512;
      float4 xv[8];
      float s1 = 0.f, s2 = 0.f;
#pragma unroll
      for (int k = 0; k < 8; ++k) {
        int col = li * 4 + k * 64;
        float4 v = *(const float4*)&hrow[col];
        float4 bb = *(const float4*)&ob1[col];
        v.x += bb.x; v.y += bb.y; v.z += bb.z; v.w += bb.w;
        xv[k] = v;
        s1 += v.x + v.y + v.z + v.w;
        s2 += v.x * v.x + v.y * v.y + v.z * v.z + v.w * v.w;
      }
#pragma unroll
      for (int off = 1; off < 16; off <<= 1) {
        s1 += __shfl_xor(s1, off, 64);
        s2 += __shfl_xor(s2, off, 64);
      }
      float mean = s1 * (1.f / 512.f);
      float var = s2 * (1.f / 512.f) - mean * mean;
      float rstd = rsqrtf(var + 1e-5f);
#pragma unroll
      for (int k = 0; k < 8; ++k) {
        int col = li * 4 + k * 64;
        float4 gg = *(const float4*)&og[col];
        float4 tt = *(const float4*)&obt[col];
        short4v pk;
        pk.x = (short)f2bf(siluf((xv[k].x - mean) * rstd * gg.x + tt.x));
        pk.y = (short)f2bf(siluf((xv[k].y - mean) * rstd * gg.y + tt.y));
        pk.z = (short)f2bf(siluf((xv[k].z - mean) * rstd * gg.z + tt.z));
        pk.w = (short)f2bf(siluf((xv[k].w - mean) * rstd * gg.w + tt.w));
        *(short4v*)((char*)sB + g * 1040 + li * 8 + k * 128) = pk;
      }
    } else {
      short4v z = {0, 0, 0, 0};
#pragma unroll
      for (int k = 0; k < 8; ++k) {
        *(short4v*)((char*)sB + g * 1040 + li * 8 + k * 128) = z;
      }
    }
  }
  __syncthreads();
  // ---- phase 2: gemm2 16x256 (rows 8-15 zero), K=512, A from LDS
  int w = tid >> 6, lane = tid & 63;
  int m = lane & 15, quad = lane >> 4;
  floatx4 acc[4];
#pragma unroll
  for (int nt = 0; nt < 4; ++nt) acc[nt] = {0.f, 0.f, 0.f, 0.f};
#pragma unroll
  for (int kc = 0; kc < 16; ++kc) {
    short8v af = *(const short8v*)((const char*)sB + m * 1040 + quad * 16 + kc * 64);
#pragma unroll
    for (int nt = 0; nt < 4; ++nt) {
      const unsigned short* bp = OW2BT + (size_t)(w * 64 + nt * 16 + m) * 512 + quad * 8;
      short8v bf = *(const short8v*)&bp[kc * 32];
      acc[nt] = __builtin_amdgcn_mfma_f32_16x16x32_bf16(af, bf, acc[nt], 0, 0, 0);
    }
  }
  // ---- phase 3: silu(+ob2) * ow3, reduce over 256 cols per row
  float pz[4];
#pragma unroll
  for (int r = 0; r < 4; ++r) pz[r] = 0.f;
#pragma unroll
  for (int nt = 0; nt < 4; ++nt) {
    int col = w * 64 + nt * 16 + m;
    float c2 = ob2[col], w3 = ow3[col];
#pragma unroll
    for (int r = 0; r < 4; ++r) pz[r] += siluf(acc[nt][r] + c2) * w3;
  }
#pragma unroll
  for (int r = 0; r < 4; ++r) {
#pragma unroll
    for (int off = 1; off < 16; off <<= 1) pz[r] += __shfl_xor(pz[r], off, 64);
    if (m == 0) sD[(quad * 4 + r) * 4 + w] = pz[r];
  }
  __syncthreads();
  if (tid < 8) {
    out[b0 + tid] = sD[tid * 4] + sD[tid * 4 + 1] + sD[tid * 4 + 2] + sD[tid * 4 + 3] + ob3[0];
  }
}

// ---------------------------------------------------------------------------
extern "C" void kernel_launch(void* const* d_in, const int* in_sizes, int n_in,
                              void* d_out, int out_size, void* d_ws, size_t ws_size,
                              hipStream_t stream) {
  const int* cand_tok = (const int*)d_in[0];
  const int* ctx_tok = (const int*)d_in[1];
  const int* hist_tok = (const int*)d_in[2];
  const int* hist_pos = (const int*)d_in[3];
  const int* hist_grp = (const int*)d_in[4];
  const int* cand_mask = (const int*)d_in[5];
  const int* ctx_mask = (const int*)d_in[6];
  const int* hist_mask = (const int*)d_in[7];
  const float* hist_times = (const float*)d_in[8];
  const float* dense_feat = (const float*)d_in[9];
  const float* tok_emb = (const float*)d_in[10];
  const float* pos_emb = (const float*)d_in[11];
  const float* grp_emb = (const float*)d_in[12];
  const float* time_w1 = (const float*)d_in[13];
  const float* time_b1 = (const float*)d_in[14];
  const float* time_w2 = (const float*)d_in[15];
  const float* time_b2 = (const float*)d_in[16];
  const float* comp_w = (const float*)d_in[17];
  const float* comp_b = (const float*)d_in[18];
  const float* comp_g = (const float*)d_in[19];
  const float* comp_bt = (const float*)d_in[20];
  const float* dense_w = (const float*)d_in[21];
  const float* dense_b = (const float*)d_in[22];
  const float* dense_g = (const float*)d_in[23];
  const float* dense_bt = (const float*)d_in[24];
  const float* query_w = (const float*)d_in[25];
  const float* query_b = (const float*)d_in[26];
  const float* query_g = (const float*)d_in[27];
  const float* query_bt = (const float*)d_in[28];
  const float* out_w1 = (const float*)d_in[29];
  const float* out_b1 = (const float*)d_in[30];
  const float* out_g = (const float*)d_in[31];
  const float* out_bt = (const float*)d_in[32];
  const float* out_w2 = (const float*)d_in[33];
  const float* out_b2 = (const float*)d_in[34];
  const float* out_w3 = (const float*)d_in[35];
  const float* out_b3 = (const float*)d_in[36];
  float* out = (float*)d_out;

  // Workspace — validated 4,950,016-float footprint (round-0 layout).
  float* ws = (float*)d_ws;
  float* E = ws;                                     // 640
  float* CC = ws + 640;                              // 5632 (ends 6272)
  float* Fs = ws + 6272;                             // 640 (ends 6912)
  float* gvecs = ws + 6912;                          // 512 (ends 7424, pad 8192)
  float* query = ws + 8192;                          // 262144
  unsigned short* OW2BT = (unsigned short*)(ws + 1318912);   // 65536 fl
  unsigned short* QWBT = (unsigned short*)(ws + 1384448);    // 57344 fl
  unsigned short* DWBT = (unsigned short*)(ws + 1441792);    // 65536 fl
  unsigned short* DB = (unsigned short*)(ws + 1507328);      // 262144 fl
  float* H1 = ws + 2099200;                          // 1048576
  unsigned short* FB = (unsigned short*)(ws + 3147776);      // 1441792 fl
  unsigned short* OW1BT = (unsigned short*)(ws + 4589568);   // 360448 fl

  k0ab<<<9, 256, 0, stream>>>(time_w1, time_b1, time_w2, time_b2,
                              grp_emb, comp_w, comp_b, E, Fs, gvecs);
  k0c_fit<<<1, 512, 0, stream>>>(Fs, gvecs, comp_g, comp_bt, CC);
  k_conv<<<3696, 256, 0, stream>>>(out_w1, out_w2, query_w, dense_w, dense_feat,
                                   OW1BT, OW2BT, QWBT, DWBT, DB);
  k_candctx<<<B_, 256, 0, stream>>>(cand_tok, ctx_tok, cand_mask, ctx_mask,
                                    tok_emb, FB);
  k_comp_pow<<<B_, 256, 0, stream>>>(hist_times, hist_grp, hist_mask, CC, FB);
  k_dln<<<B_ / 8, 256, 0, stream>>>(DB, DWBT, dense_b, dense_g, dense_bt, FB);
  k_query_mfma<<<B_ / 8, 256, 0, stream>>>(FB, QWBT, query_b, query_g, query_bt, query);
  k_attn4<<<B_, 256, 0, stream>>>(hist_tok, hist_pos, hist_grp, hist_mask, hist_times,
                                  tok_emb, pos_emb, grp_emb, query, E, FB);
  k_gemm1<<<512, 256, 0, stream>>>(FB, OW1BT, H1);
  k_ep2<<<B_ / 8, 256, 0, stream>>>(H1, out_b1, out_g, out_bt,
                                    OW2BT, out_b2, out_w3, out_b3, out);
}